// Round 19
// baseline (88.570 us; speedup 1.0000x reference)
//
#include <hip/hip_runtime.h>
#include <hip/hip_bf16.h>

typedef __bf16 bf16x8 __attribute__((ext_vector_type(8)));
typedef float  f32x4  __attribute__((ext_vector_type(4)));

#define IN_F   4096
#define OUT_F  4096
#define RANK   32

__device__ __forceinline__ bf16x8 cvt8(float4 a, float4 b) {
    bf16x8 r;
    r[0] = (__bf16)a.x; r[1] = (__bf16)a.y; r[2] = (__bf16)a.z; r[3] = (__bf16)a.w;
    r[4] = (__bf16)b.x; r[5] = (__bf16)b.y; r[6] = (__bf16)b.z; r[7] = (__bf16)b.w;
    return r;
}

// ---------------- Kernel 1: Hpart[ks] = (X @ V^T) * S  — 32 waves/CU test ----------
// 2048 blocks x 256 thr, __launch_bounds__(256,8): 8 blocks/CU, 32 waves/CU —
// the probe's concurrency, which is the ONLY untested axis (probe: 6.4 TB/s at
// 32 w/CU; every K1 so far: 3.4-3.7 TB/s at 8-16 w/CU). Zero hot-loop LDS, zero
// barriers: wave = 16 tokens x 256-feat quarter x ALL 32 ranks, plain VGPR
// fragment loads, 8 K-steps x 2 MFMA. Epilogue: 2 KB LDS reduce of the block's
// 4 feat-quarters -> one Hpart slice write. X read once (128 MB); V re-reads
// come from L2 (V = 512 KB, resident per XCD).
__global__ __launch_bounds__(256, 8)
void lora_h(const float* __restrict__ X, const float* __restrict__ S,
            const float* __restrict__ V, float* __restrict__ Hpart)
{
    __shared__ float Hp[4][16][33];     // 8.4 KB: per-wave partials, padded

    const int tid  = threadIdx.x;
    const int wave = tid >> 6;          // feat quarter
    const int lane = tid & 63;
    const int r    = lane & 15;
    const int kg   = lane >> 4;

    const int t0 = blockIdx.x * 16;
    const int f0 = blockIdx.y * 1024 + wave * 256 + kg * 8;

    const float* xrow  = X + (size_t)(t0 + r) * IN_F + f0;
    const float* v0row = V + (size_t)r        * IN_F + f0;
    const float* v1row = V + (size_t)(16 + r) * IN_F + f0;

    f32x4 a0 = {0.f, 0.f, 0.f, 0.f};
    f32x4 a1 = {0.f, 0.f, 0.f, 0.f};

    #pragma unroll
    for (int s = 0; s < 8; ++s) {       // 8 K-steps x 32 feats = 256
        const float4* xp  = reinterpret_cast<const float4*>(xrow  + s * 32);
        const float4* vp0 = reinterpret_cast<const float4*>(v0row + s * 32);
        const float4* vp1 = reinterpret_cast<const float4*>(v1row + s * 32);
        float4 x0 = xp[0],  x1 = xp[1];
        float4 va = vp0[0], vb = vp0[1];
        float4 vc = vp1[0], vd = vp1[1];
        bf16x8 xb = cvt8(x0, x1);
        // A = X (m = token), B = V (n = rank-in-half)
        a0 = __builtin_amdgcn_mfma_f32_16x16x32_bf16(xb, cvt8(va, vb), a0, 0, 0, 0);
        a1 = __builtin_amdgcn_mfma_f32_16x16x32_bf16(xb, cvt8(vc, vd), a1, 0, 0, 0);
    }

    // D: col(n=rank) = r, row(m=token) = kg*4+j
    #pragma unroll
    for (int j = 0; j < 4; ++j) {
        Hp[wave][kg * 4 + j][r]      = a0[j];
        Hp[wave][kg * 4 + j][16 + r] = a1[j];
    }
    __syncthreads();

    // reduce the block's 4 feat-quarters, apply S, write slice partial
    float* dst = Hpart + (size_t)blockIdx.y * (8192 * RANK) + (size_t)t0 * RANK;
    #pragma unroll
    for (int i = tid; i < 16 * RANK; i += 256) {
        const int tok = i >> 5, rk = i & 31;
        const float sum = Hp[0][tok][rk] + Hp[1][tok][rk]
                        + Hp[2][tok][rk] + Hp[3][tok][rk];
        dst[i] = sum * S[rk];           // SCALING == 1.0 folded
    }
}

// ---------------- Fallback (small ws): naive H ----------------
__global__ __launch_bounds__(256)
void lora_h_naive(const float* __restrict__ X, const float* __restrict__ S,
                  const float* __restrict__ V, float* __restrict__ H)
{
    const int idx = blockIdx.x * 256 + threadIdx.x;   // 262144 = 8192*32
    const int tok = idx >> 5, rk = idx & 31;
    float acc = 0.f;
    for (int f = 0; f < IN_F; ++f)
        acc += X[(size_t)tok * IN_F + f] * V[(size_t)rk * IN_F + f];
    H[idx] = acc * S[rk];
}

// ---------------- Kernel 1.5: H = sum_k Hpart[k] ----------------
template <int NKS>
__global__ __launch_bounds__(256)
void lora_hred(const float* __restrict__ Hpart, float* __restrict__ H)
{
    const int idx = blockIdx.x * 256 + threadIdx.x;   // float4 idx, 65536
    const float4* hp = reinterpret_cast<const float4*>(Hpart);
    float4 v = hp[idx];
    #pragma unroll
    for (int k = 1; k < NKS; ++k) {
        float4 p = hp[(size_t)k * 65536 + idx];
        v.x += p.x; v.y += p.y; v.z += p.z; v.w += p.w;
    }
    reinterpret_cast<float4*>(H)[idx] = v;
}

// ---------------- Kernel 2 (proven ~9.5 µs): Out = H @ U^T ----------------
__global__ __launch_bounds__(256, 4)
void lora_out(const float* __restrict__ H, const float* __restrict__ U,
              float* __restrict__ Out)
{
    __shared__ float Hs[32][33];

    const int tid  = threadIdx.x;
    const int wave = tid >> 6;
    const int lane = tid & 63;
    const int r    = lane & 15;
    const int kg   = lane >> 4;

    const int tt = blockIdx.x >> 2;
    const int cq = blockIdx.x & 3;
    const int t0 = tt * 32;

    {
        float4 v = reinterpret_cast<const float4*>(H + (size_t)t0 * RANK)[tid];
        const int tok = tid >> 3;
        const int rr  = (tid & 7) * 4;
        Hs[tok][rr] = v.x; Hs[tok][rr + 1] = v.y;
        Hs[tok][rr + 2] = v.z; Hs[tok][rr + 3] = v.w;
    }
    __syncthreads();

    bf16x8 hb[2];
    #pragma unroll
    for (int a = 0; a < 2; ++a)
        #pragma unroll
        for (int j = 0; j < 8; ++j) hb[a][j] = (__bf16)Hs[a * 16 + r][kg * 8 + j];

    const int wc0 = cq * 1024 + wave * 256;

    #pragma unroll
    for (int g = 0; g < 4; ++g) {
        float4 u0[4], u1[4];
        #pragma unroll
        for (int b = 0; b < 4; ++b) {
            const float4* up = reinterpret_cast<const float4*>(
                U + (size_t)(wc0 + g * 64 + b * 16 + r) * RANK + kg * 8);
            u0[b] = up[0];
            u1[b] = up[1];
        }
        #pragma unroll
        for (int b = 0; b < 4; ++b) {
            bf16x8 ub = cvt8(u0[b], u1[b]);
            #pragma unroll
            for (int a = 0; a < 2; ++a) {
                f32x4 d = {0.f, 0.f, 0.f, 0.f};
                d = __builtin_amdgcn_mfma_f32_16x16x32_bf16(ub, hb[a], d, 0, 0, 0);
                *reinterpret_cast<float4*>(
                    Out + (size_t)(t0 + a * 16 + r) * OUT_F
                        + wc0 + g * 64 + b * 16 + kg * 4)
                    = *reinterpret_cast<float4*>(&d);
            }
        }
    }
}

extern "C" void kernel_launch(void* const* d_in, const int* in_sizes, int n_in,
                              void* d_out, int out_size, void* d_ws, size_t ws_size,
                              hipStream_t stream) {
    const float* X = (const float*)d_in[0];
    const float* U = (const float*)d_in[1];
    const float* S = (const float*)d_in[2];
    const float* V = (const float*)d_in[3];
    float* Out = (float*)d_out;

    float* H     = (float*)d_ws;                 // 1 MB reduced H
    float* Hpart = (float*)d_ws + 262144;        // 4 MB partials (KS=4)

    if (ws_size >= (size_t)5 * 1024 * 1024) {
        lora_h<<<dim3(512, 4), 256, 0, stream>>>(X, S, V, Hpart);
        lora_hred<4><<<256, 256, 0, stream>>>(Hpart, H);
        lora_out<<<1024, 256, 0, stream>>>(H, U, Out);
    } else {
        lora_h_naive<<<1024, 256, 0, stream>>>(X, S, V, H);
        lora_out<<<1024, 256, 0, stream>>>(H, U, Out);
    }
}

// Round 20
// 62.131 us; speedup vs baseline: 1.4255x; 1.4255x over previous
//
#include <hip/hip_runtime.h>
#include <hip/hip_bf16.h>

typedef __bf16 bf16x8 __attribute__((ext_vector_type(8)));
typedef float  f32x4  __attribute__((ext_vector_type(4)));

#define IN_F   4096
#define OUT_F  4096
#define RANK   32

__device__ __forceinline__ bf16x8 cvt8(float4 a, float4 b) {
    bf16x8 r;
    r[0] = (__bf16)a.x; r[1] = (__bf16)a.y; r[2] = (__bf16)a.z; r[3] = (__bf16)a.w;
    r[4] = (__bf16)b.x; r[5] = (__bf16)b.y; r[6] = (__bf16)b.z; r[7] = (__bf16)b.w;
    return r;
}

// ---------------- Kernel 1: Hpart[ks] = (X @ V^T) * S ----------------
// The round-19 lesson applied: 32 waves/CU (proven 5.0 TB/s) AND minimal
// traffic (160 MB) simultaneously. 512 thr (8 waves), block = 128 tokens x
// SL feats. Wave = 16 tokens x ALL 32 ranks -> X read exactly once (128 MB);
// V staged once/block to a small bf16 LDS tile (32 MB total). KS=8: VL=33 KB
// -> 4 blocks/CU = 32 waves/CU. Zero hot-loop barriers; V ds_reads padded
// (+8 bf16 -> 2-way banks, free per m136). acc = 2 f32x4; VGPR ~60.
template <int KS, int MINW>
__global__ __launch_bounds__(512, MINW)
void lora_h(const float* __restrict__ X, const float* __restrict__ S,
            const float* __restrict__ V, float* __restrict__ Hpart)
{
    constexpr int SL    = IN_F / KS;        // feats per slice
    constexpr int STEPS = SL / 32;          // K-steps
    constexpr int VPAD  = 8;

    __shared__ __bf16 VL[32][SL + VPAD];    // KS=8: 33.3 KB

    const int tid  = threadIdx.x;
    const int wave = tid >> 6;              // 0..7 = token 16-tile
    const int lane = tid & 63;
    const int r    = lane & 15;
    const int kg   = lane >> 4;

    const int t0    = blockIdx.x * 128;
    const int fbase = blockIdx.y * SL;

    // ---- stage V slice once: 32 rows x SL feats fp32 -> bf16 LDS ----
    {
        constexpr int UNITS = 32 * (SL / 16);           // (row, 16-feat) units
        for (int u = tid; u < UNITS; u += 512) {
            const int row = u / (SL / 16);
            const int fq  = u % (SL / 16);
            const float4* vp = reinterpret_cast<const float4*>(
                V + (size_t)row * IN_F + fbase + fq * 16);
            float4 a = vp[0], b = vp[1], c = vp[2], d = vp[3];
            *reinterpret_cast<bf16x8*>(&VL[row][fq * 16])     = cvt8(a, b);
            *reinterpret_cast<bf16x8*>(&VL[row][fq * 16 + 8]) = cvt8(c, d);
        }
    }
    __syncthreads();                        // the kernel's only barrier

    const float s_lo = S[r];
    const float s_hi = S[16 + r];

    const float* xrow = X + (size_t)(t0 + wave * 16 + r) * IN_F + fbase + kg * 8;

    f32x4 a0 = {0.f, 0.f, 0.f, 0.f};
    f32x4 a1 = {0.f, 0.f, 0.f, 0.f};

    #pragma unroll 4
    for (int s = 0; s < STEPS; ++s) {
        const float4* xp = reinterpret_cast<const float4*>(xrow + s * 32);
        float4 x0 = xp[0], x1 = xp[1];
        bf16x8 vb0 = *reinterpret_cast<const bf16x8*>(&VL[r]     [s * 32 + kg * 8]);
        bf16x8 vb1 = *reinterpret_cast<const bf16x8*>(&VL[16 + r][s * 32 + kg * 8]);
        bf16x8 xb = cvt8(x0, x1);
        // A = X (m = token), B = V (n = rank-in-half)
        a0 = __builtin_amdgcn_mfma_f32_16x16x32_bf16(xb, vb0, a0, 0, 0, 0);
        a1 = __builtin_amdgcn_mfma_f32_16x16x32_bf16(xb, vb1, a1, 0, 0, 0);
    }

    // D: token = wave*16 + kg*4 + j, rank = r / 16+r. Direct global store.
    float* Hq = Hpart + (size_t)blockIdx.y * (8192 * RANK)
                      + (size_t)(t0 + wave * 16) * RANK;
    #pragma unroll
    for (int j = 0; j < 4; ++j) {
        const int tok = kg * 4 + j;
        Hq[(size_t)tok * RANK + r]      = a0[j] * s_lo;
        Hq[(size_t)tok * RANK + 16 + r] = a1[j] * s_hi;
    }
}

// ---------------- Fallback (small ws): naive H ----------------
__global__ __launch_bounds__(256)
void lora_h_naive(const float* __restrict__ X, const float* __restrict__ S,
                  const float* __restrict__ V, float* __restrict__ H)
{
    const int idx = blockIdx.x * 256 + threadIdx.x;   // 262144 = 8192*32
    const int tok = idx >> 5, rk = idx & 31;
    float acc = 0.f;
    for (int f = 0; f < IN_F; ++f)
        acc += X[(size_t)tok * IN_F + f] * V[(size_t)rk * IN_F + f];
    H[idx] = acc * S[rk];
}

// ---------------- Kernel 1.5: H = sum_k Hpart[k] ----------------
template <int NKS>
__global__ __launch_bounds__(256)
void lora_hred(const float* __restrict__ Hpart, float* __restrict__ H)
{
    const int idx = blockIdx.x * 256 + threadIdx.x;   // float4 idx, 65536
    const float4* hp = reinterpret_cast<const float4*>(Hpart);
    float4 v = hp[idx];
    #pragma unroll
    for (int k = 1; k < NKS; ++k) {
        float4 p = hp[(size_t)k * 65536 + idx];
        v.x += p.x; v.y += p.y; v.z += p.z; v.w += p.w;
    }
    reinterpret_cast<float4*>(H)[idx] = v;
}

// ---------------- Kernel 2 (proven ~9.5 µs): Out = H @ U^T ----------------
__global__ __launch_bounds__(256, 4)
void lora_out(const float* __restrict__ H, const float* __restrict__ U,
              float* __restrict__ Out)
{
    __shared__ float Hs[32][33];

    const int tid  = threadIdx.x;
    const int wave = tid >> 6;
    const int lane = tid & 63;
    const int r    = lane & 15;
    const int kg   = lane >> 4;

    const int tt = blockIdx.x >> 2;
    const int cq = blockIdx.x & 3;
    const int t0 = tt * 32;

    {
        float4 v = reinterpret_cast<const float4*>(H + (size_t)t0 * RANK)[tid];
        const int tok = tid >> 3;
        const int rr  = (tid & 7) * 4;
        Hs[tok][rr] = v.x; Hs[tok][rr + 1] = v.y;
        Hs[tok][rr + 2] = v.z; Hs[tok][rr + 3] = v.w;
    }
    __syncthreads();

    bf16x8 hb[2];
    #pragma unroll
    for (int a = 0; a < 2; ++a)
        #pragma unroll
        for (int j = 0; j < 8; ++j) hb[a][j] = (__bf16)Hs[a * 16 + r][kg * 8 + j];

    const int wc0 = cq * 1024 + wave * 256;

    #pragma unroll
    for (int g = 0; g < 4; ++g) {
        float4 u0[4], u1[4];
        #pragma unroll
        for (int b = 0; b < 4; ++b) {
            const float4* up = reinterpret_cast<const float4*>(
                U + (size_t)(wc0 + g * 64 + b * 16 + r) * RANK + kg * 8);
            u0[b] = up[0];
            u1[b] = up[1];
        }
        #pragma unroll
        for (int b = 0; b < 4; ++b) {
            bf16x8 ub = cvt8(u0[b], u1[b]);
            #pragma unroll
            for (int a = 0; a < 2; ++a) {
                f32x4 d = {0.f, 0.f, 0.f, 0.f};
                d = __builtin_amdgcn_mfma_f32_16x16x32_bf16(ub, hb[a], d, 0, 0, 0);
                *reinterpret_cast<float4*>(
                    Out + (size_t)(t0 + a * 16 + r) * OUT_F
                        + wc0 + g * 64 + b * 16 + kg * 4)
                    = *reinterpret_cast<float4*>(&d);
            }
        }
    }
}

extern "C" void kernel_launch(void* const* d_in, const int* in_sizes, int n_in,
                              void* d_out, int out_size, void* d_ws, size_t ws_size,
                              hipStream_t stream) {
    const float* X = (const float*)d_in[0];
    const float* U = (const float*)d_in[1];
    const float* S = (const float*)d_in[2];
    const float* V = (const float*)d_in[3];
    float* Out = (float*)d_out;

    float* H     = (float*)d_ws;                 // 1 MB reduced H
    float* Hpart = (float*)d_ws + 262144;        // up to 8 MB partials

    if (ws_size >= (size_t)10 * 1024 * 1024) {
        // KS=8: 512 blocks (64 x 8), 33 KB LDS -> 4 blocks/CU, 32 waves/CU
        lora_h<8, 8><<<dim3(64, 8), 512, 0, stream>>>(X, S, V, Hpart);
        lora_hred<8><<<256, 256, 0, stream>>>(Hpart, H);
        lora_out<<<1024, 256, 0, stream>>>(H, U, Out);
    } else if (ws_size >= (size_t)5 * 1024 * 1024) {
        // KS=4: 66 KB LDS -> 2 blocks/CU, 16 waves/CU (R17-class fallback)
        lora_h<4, 4><<<dim3(64, 4), 512, 0, stream>>>(X, S, V, Hpart);
        lora_hred<4><<<256, 256, 0, stream>>>(Hpart, H);
        lora_out<<<1024, 256, 0, stream>>>(H, U, Out);
    } else {
        lora_h_naive<<<1024, 256, 0, stream>>>(X, S, V, H);
        lora_out<<<1024, 256, 0, stream>>>(H, U, Out);
    }
}